// Round 2
// baseline (85.163 us; speedup 1.0000x reference)
//
#include <hip/hip_runtime.h>
#include <math.h>

#define DIMS 128
#define KNEG 256
#define INV_TEMP 20.0f   // 1 / 0.05
#define EPSN 1e-12f

// One block (256 threads = 8 half-waves of 32 lanes) per output row n.
// Fully-unrolled gather loop: scheduler keeps several 1 KB gathers in
// flight per wave (ILP) on top of 8-wave/SIMD TLP.
__global__ __launch_bounds__(256, 8) void ssl_row_kernel(
    const float* __restrict__ out_emb,   // [N, 128]
    const float* __restrict__ table,     // [M, 128] raw (unnormalized)
    const float* __restrict__ w,         // [N]
    const int*   __restrict__ tgt,       // [N]
    const int*   __restrict__ negs,      // [N, 256]
    float*       __restrict__ loss_out,  // [N] = loss_per * w
    int max_row)                         // = M-1 (clip bound)
{
    const int n = blockIdx.x;
    const int t = threadIdx.x;

    __shared__ __align__(16) float q_lds[DIMS];
    __shared__ float logits[KNEG + 1];
    __shared__ int   nid[KNEG];
    __shared__ float red[8];

    const float wn = w[n];
    if (wn == 0.0f) {            // w==0 rows contribute 0 to the weighted sum
        if (t == 0) loss_out[n] = 0.0f;
        return;
    }

    // ---- normalize q row into LDS; stage neg ids ----
    float x = 0.0f;
    if (t < DIMS) x = out_emb[(size_t)n * DIMS + t];
    float ss = x * x;
    #pragma unroll
    for (int m = 1; m < 64; m <<= 1) ss += __shfl_xor(ss, m, 64);
    if ((t & 63) == 0) red[t >> 6] = ss;
    if (t < KNEG) nid[t] = negs[(size_t)n * KNEG + t];
    __syncthreads();
    const float inv_qn = 1.0f / fmaxf(sqrtf(red[0] + red[1]), EPSN);
    if (t < DIMS) q_lds[t] = x * inv_qn;
    __syncthreads();

    // ---- gather + logits ----
    const int hw   = t >> 5;   // half-wave id 0..7
    const int lane = t & 31;   // lane in half-wave
    const float4 qv = *(const float4*)(q_lds + lane * 4);
    const int tgtn = tgt[n];

    auto rowp = [&](int id) -> const float4* {
        int i = id - 1; i = i < 0 ? 0 : (i > max_row ? max_row : i);
        return (const float4*)(table + (size_t)i * DIMS);
    };

    auto red_store = [&](float4 a, float4 b, int j) {
        float dq1 = qv.x*a.x + qv.y*a.y + qv.z*a.z + qv.w*a.w;
        float de1 = a.x*a.x + a.y*a.y + a.z*a.z + a.w*a.w;
        float dq2 = qv.x*b.x + qv.y*b.y + qv.z*b.z + qv.w*b.w;
        float de2 = b.x*b.x + b.y*b.y + b.z*b.z + b.w*b.w;
        #pragma unroll
        for (int m = 1; m < 32; m <<= 1) {
            dq1 += __shfl_xor(dq1, m, 64);
            de1 += __shfl_xor(de1, m, 64);
            dq2 += __shfl_xor(dq2, m, 64);
            de2 += __shfl_xor(de2, m, 64);
        }
        if (lane == 0) {
            logits[j]     = dq1 / fmaxf(sqrtf(de1), EPSN) * INV_TEMP;
            logits[j + 8] = dq2 / fmaxf(sqrtf(de2), EPSN) * INV_TEMP;
        }
    };

    // tail row (j == 256), hw 0 only: issue its load before the main loop so
    // its latency hides under the 32 main-loop rows.
    float4 et;
    if (hw == 0) et = rowp(nid[KNEG - 1])[lane];

    // 16 pairs per half-wave: j1 = hw + 16p, j2 = j1 + 8. Fully unrolled.
    #pragma unroll
    for (int p = 0; p < 16; ++p) {
        const int j1  = hw + (p << 4);
        const int id1 = (p == 0 && hw == 0) ? tgtn : nid[j1 - 1];
        const int id2 = nid[j1 + 7];
        const float4 a = rowp(id1)[lane];
        const float4 b = rowp(id2)[lane];
        red_store(a, b, j1);
    }

    if (hw == 0) {   // reduce the tail row
        float dq1 = qv.x*et.x + qv.y*et.y + qv.z*et.z + qv.w*et.w;
        float de1 = et.x*et.x + et.y*et.y + et.z*et.z + et.w*et.w;
        #pragma unroll
        for (int m = 1; m < 32; m <<= 1) {
            dq1 += __shfl_xor(dq1, m, 64);
            de1 += __shfl_xor(de1, m, 64);
        }
        if (lane == 0) logits[KNEG] = dq1 / fmaxf(sqrtf(de1), EPSN) * INV_TEMP;
    }
    __syncthreads();

    // ---- stable LSE over 257 logits ----
    float mx = logits[t];
    if (t == 0) mx = fmaxf(mx, logits[KNEG]);
    #pragma unroll
    for (int m = 1; m < 64; m <<= 1) mx = fmaxf(mx, __shfl_xor(mx, m, 64));
    if ((t & 63) == 0) red[t >> 6] = mx;
    __syncthreads();
    if (t == 0) red[4] = fmaxf(fmaxf(red[0], red[1]), fmaxf(red[2], red[3]));
    __syncthreads();
    mx = red[4];

    float p = expf(logits[t] - mx);
    if (t == 0) p += expf(logits[KNEG] - mx);
    #pragma unroll
    for (int m = 1; m < 64; m <<= 1) p += __shfl_xor(p, m, 64);
    if ((t & 63) == 0) red[t >> 6] = p;
    __syncthreads();
    if (t == 0) {
        const float s   = red[0] + red[1] + red[2] + red[3];
        const float lse = mx + logf(s);
        loss_out[n] = (lse - logits[0]) * wn;   // loss_per * w
    }
}

// Deterministic final reduction: sum(loss*w) / sum(w)
__global__ __launch_bounds__(256) void ssl_reduce_kernel(
    const float* __restrict__ loss,  // [N]
    const float* __restrict__ w,     // [N]
    float* __restrict__ out, int n)
{
    __shared__ float red[8];
    const int t = threadIdx.x;
    float sl = 0.0f, sw = 0.0f;
    for (int i = t; i < n; i += 256) { sl += loss[i]; sw += w[i]; }
    #pragma unroll
    for (int m = 1; m < 64; m <<= 1) {
        sl += __shfl_xor(sl, m, 64);
        sw += __shfl_xor(sw, m, 64);
    }
    if ((t & 63) == 0) { red[t >> 6] = sl; red[4 + (t >> 6)] = sw; }
    __syncthreads();
    if (t == 0) {
        const float SL = red[0] + red[1] + red[2] + red[3];
        const float SW = red[4] + red[5] + red[6] + red[7];
        out[0] = SL / SW;
    }
}

extern "C" void kernel_launch(void* const* d_in, const int* in_sizes, int n_in,
                              void* d_out, int out_size, void* d_ws, size_t ws_size,
                              hipStream_t stream) {
    const float* out_emb = (const float*)d_in[0];   // [16,256,128]
    const float* table   = (const float*)d_in[1];   // [1000001,128]
    const float* w       = (const float*)d_in[2];   // [16,256]
    const int*   tgt     = (const int*)d_in[3];     // [16,256]
    const int*   negs    = (const int*)d_in[4];     // [4096,256]

    const int N = in_sizes[2];                       // 4096
    const int rows = in_sizes[1] / DIMS;             // 1000001
    const int max_row = rows - 1;

    float* loss_ws = (float*)d_ws;                   // N floats

    ssl_row_kernel<<<N, 256, 0, stream>>>(out_emb, table, w, tgt, negs, loss_ws, max_row);
    ssl_reduce_kernel<<<1, 256, 0, stream>>>(loss_ws, w, (float*)d_out, N);
}